// Round 1
// baseline (623.659 us; speedup 1.0000x reference)
//
#include <hip/hip_runtime.h>
#include <hip/hip_bf16.h>
#include <cstdint>
#include <cstddef>

#define B_DIM  8192
#define D_DIM  1024
#define H_DIM  4096
#define H2_DIM 8192

using bf16 = __hip_bfloat16;
typedef __attribute__((ext_vector_type(8))) short bf16x8;   // 8 bf16 in 4 VGPRs
typedef __attribute__((ext_vector_type(4))) float f32x4;    // MFMA accumulator

// ---------------------------------------------------------------- cast x -> bf16
__global__ __launch_bounds__(256) void cast_f32_to_bf16(const float* __restrict__ in,
                                                        bf16* __restrict__ out, int n_vec8) {
    int i = blockIdx.x * 256 + threadIdx.x;
    if (i >= n_vec8) return;
    const float4* src = reinterpret_cast<const float4*>(in) + (size_t)i * 2;
    float4 a = src[0], b = src[1];
    union { bf16 h[8]; int4 u; } r;
    r.h[0] = __float2bfloat16(a.x); r.h[1] = __float2bfloat16(a.y);
    r.h[2] = __float2bfloat16(a.z); r.h[3] = __float2bfloat16(a.w);
    r.h[4] = __float2bfloat16(b.x); r.h[5] = __float2bfloat16(b.y);
    r.h[6] = __float2bfloat16(b.z); r.h[7] = __float2bfloat16(b.w);
    reinterpret_cast<int4*>(out)[i] = r.u;
}

// ---------------------------------------------------------------- router p = sigmoid(x.Wr + br)
__global__ __launch_bounds__(256) void router_kernel(const float* __restrict__ x,
                                                     const float* __restrict__ Wr,
                                                     const float* __restrict__ br,
                                                     float* __restrict__ p) {
    int wave = threadIdx.x >> 6, lane = threadIdx.x & 63;
    int row = blockIdx.x * 4 + wave;
    const float* xr = x + (size_t)row * D_DIM;
    float sum = 0.f;
#pragma unroll
    for (int it = 0; it < 4; ++it) {
        int k = it * 256 + lane * 4;
        float4 xv = *reinterpret_cast<const float4*>(xr + k);
        float4 wv = *reinterpret_cast<const float4*>(Wr + k);
        sum += xv.x * wv.x + xv.y * wv.y + xv.z * wv.z + xv.w * wv.w;
    }
#pragma unroll
    for (int off = 32; off >= 1; off >>= 1) sum += __shfl_down(sum, off, 64);
    if (lane == 0) p[row] = 1.f / (1.f + expf(-(sum + br[0])));
}

// ---------------------------------------------------------------- transpose f32 [R][C] -> bf16 dst[c*dstLD + r]
__global__ __launch_bounds__(256) void transpose_cast_kernel(const float* __restrict__ src,
                                                             int R, int C,
                                                             bf16* __restrict__ dst, int dstLD) {
    __shared__ float tile[32][33];
    int c0 = blockIdx.x * 32, r0 = blockIdx.y * 32;
    int tx = threadIdx.x & 31, ty = threadIdx.x >> 5;  // ty: 0..7
#pragma unroll
    for (int i = 0; i < 32; i += 8)
        tile[ty + i][tx] = src[(size_t)(r0 + ty + i) * C + c0 + tx];
    __syncthreads();
#pragma unroll
    for (int i = 0; i < 32; i += 8)
        dst[(size_t)(c0 + ty + i) * dstLD + r0 + tx] = __float2bfloat16(tile[tx][ty + i]);
}

// ---------------------------------------------------------------- GEMM: C = A[M,K] * Bt[N,K]^T
// EPI==1: h = bf16( relu(acc + b1cat[col]) * (col<H ? p : 1-p) )   (bf16 out, ld=N)
// EPI==0: out = acc + p*b2l[col] + (1-p)*b2r[col]                  (f32 out, ld=N)
template <int EPI>
__global__ __launch_bounds__(256) void gemm_kernel(const bf16* __restrict__ A,
                                                   const bf16* __restrict__ Bt,
                                                   void* __restrict__ Cout,
                                                   int M, int N, int K,
                                                   const float* __restrict__ p,
                                                   const float* __restrict__ bias_l,
                                                   const float* __restrict__ bias_r) {
    __shared__ __align__(16) bf16 sA[128 * 32];
    __shared__ __align__(16) bf16 sB[128 * 32];
    const int tid  = threadIdx.x;
    const int wave = tid >> 6, lane = tid & 63;
    const int wr = wave >> 1, wc = wave & 1;     // 2x2 waves of 64x64
    const int bm = blockIdx.y * 128, bn = blockIdx.x * 128;

    const bf16* Ab = A + (size_t)bm * K;
    const bf16* Bb = Bt + (size_t)bn * K;

    f32x4 acc[4][4];
#pragma unroll
    for (int m = 0; m < 4; ++m)
#pragma unroll
        for (int n = 0; n < 4; ++n) acc[m][n] = (f32x4){0.f, 0.f, 0.f, 0.f};

    const int lrow = lane & 15;
    const int kgrp = (lane >> 4) * 8;

    for (int k0 = 0; k0 < K; k0 += 32) {
        __syncthreads();   // all waves done reading LDS from previous step
        // stage A,B tiles (8KB each) via async global->LDS, 16B/lane
#pragma unroll
        for (int c = 0; c < 2; ++c) {
            const int base = wave * 2048 + c * 1024;   // wave-uniform byte base in tile
            const int off  = base + lane * 16;         // this lane's dest byte
            const int row  = off >> 6;                 // /64B per row (32 bf16)
            const int ke   = (off & 63) >> 1;          // element offset in row
            __builtin_amdgcn_global_load_lds(
                (const __attribute__((address_space(1))) uint32_t*)(Ab + (size_t)row * K + k0 + ke),
                (__attribute__((address_space(3))) uint32_t*)(sA + (base >> 1)),
                16, 0, 0);
            __builtin_amdgcn_global_load_lds(
                (const __attribute__((address_space(1))) uint32_t*)(Bb + (size_t)row * K + k0 + ke),
                (__attribute__((address_space(3))) uint32_t*)(sB + (base >> 1)),
                16, 0, 0);
        }
        __syncthreads();   // drains vmcnt(0): LDS tiles ready

        bf16x8 af[4], bq[4];
#pragma unroll
        for (int m = 0; m < 4; ++m)
            af[m] = *reinterpret_cast<const bf16x8*>(&sA[(wr * 64 + m * 16 + lrow) * 32 + kgrp]);
#pragma unroll
        for (int n = 0; n < 4; ++n)
            bq[n] = *reinterpret_cast<const bf16x8*>(&sB[(wc * 64 + n * 16 + lrow) * 32 + kgrp]);
#pragma unroll
        for (int m = 0; m < 4; ++m)
#pragma unroll
            for (int n = 0; n < 4; ++n)
                acc[m][n] = __builtin_amdgcn_mfma_f32_16x16x32_bf16(af[m], bq[n], acc[m][n], 0, 0, 0);
    }

    // epilogue: C/D layout col = lane&15, row = (lane>>4)*4 + j   [m89-verified]
    const int crow_base = bm + wr * 64 + ((lane >> 4) << 2);
    const int ccol_base = bn + wc * 64 + lrow;

    if (EPI == 1) {
        bf16* __restrict__ Hout = (bf16*)Cout;
#pragma unroll
        for (int n = 0; n < 4; ++n) {
            const int col = ccol_base + n * 16;
            const bool left = col < H_DIM;
            const float bias = left ? bias_l[col] : bias_r[col - H_DIM];
#pragma unroll
            for (int m = 0; m < 4; ++m) {
#pragma unroll
                for (int j = 0; j < 4; ++j) {
                    const int row = crow_base + m * 16 + j;
                    const float pw = p[row];
                    const float scale = left ? pw : 1.f - pw;
                    const float v = fmaxf(acc[m][n][j] + bias, 0.f) * scale;
                    Hout[(size_t)row * N + col] = __float2bfloat16(v);
                }
            }
        }
    } else {
        float* __restrict__ Co = (float*)Cout;
#pragma unroll
        for (int n = 0; n < 4; ++n) {
            const int col = ccol_base + n * 16;
            const float bl = bias_l[col];
            const float brr = bias_r[col];
#pragma unroll
            for (int m = 0; m < 4; ++m) {
#pragma unroll
                for (int j = 0; j < 4; ++j) {
                    const int row = crow_base + m * 16 + j;
                    const float pw = p[row];
                    Co[(size_t)row * N + col] = acc[m][n][j] + pw * bl + (1.f - pw) * brr;
                }
            }
        }
    }
}

// ---------------------------------------------------------------- launch
extern "C" void kernel_launch(void* const* d_in, const int* in_sizes, int n_in,
                              void* d_out, int out_size, void* d_ws, size_t ws_size,
                              hipStream_t stream) {
    const float* x   = (const float*)d_in[0];
    const float* Wr  = (const float*)d_in[1];
    const float* br  = (const float*)d_in[2];
    const float* W1l = (const float*)d_in[3];
    const float* b1l = (const float*)d_in[4];
    const float* W2l = (const float*)d_in[5];
    const float* b2l = (const float*)d_in[6];
    const float* W1r = (const float*)d_in[7];
    const float* b1r = (const float*)d_in[8];
    const float* W2r = (const float*)d_in[9];
    const float* b2r = (const float*)d_in[10];
    float* out = (float*)d_out;

    char* ws = (char*)d_ws;
    // workspace layout (160.03 MB):
    //   [0,16MB)    x_bf16 [B][D]        (dead after gemm1; reused for W2t)
    //   [16,32MB)   W1t    [2H][D] bf16
    //   [32,160MB)  h      [B][2H] bf16
    //   [160MB,+32K) p     [B] f32
    bf16*  x_bf = (bf16*)(ws);
    bf16*  W1t  = (bf16*)(ws + (size_t)(16u << 20));
    bf16*  hbuf = (bf16*)(ws + (size_t)(32u << 20));
    float* pbuf = (float*)(ws + (size_t)(160u << 20));
    bf16*  W2t  = x_bf;   // aliased: written only after gemm1 consumed x_bf

    cast_f32_to_bf16<<<(B_DIM * D_DIM / 8 + 255) / 256, 256, 0, stream>>>(x, x_bf, B_DIM * D_DIM / 8);
    router_kernel<<<B_DIM / 4, 256, 0, stream>>>(x, Wr, br, pbuf);

    // W1t[n][k]: n<H -> W1l[k][n], else W1r[k][n-H]
    transpose_cast_kernel<<<dim3(H_DIM / 32, D_DIM / 32), 256, 0, stream>>>(W1l, D_DIM, H_DIM, W1t, D_DIM);
    transpose_cast_kernel<<<dim3(H_DIM / 32, D_DIM / 32), 256, 0, stream>>>(W1r, D_DIM, H_DIM,
                                                                            W1t + (size_t)H_DIM * D_DIM, D_DIM);
    // h = relu(x @ W1cat + b1cat) * {p | 1-p}   -> bf16 [B][2H]
    gemm_kernel<1><<<dim3(H2_DIM / 128, B_DIM / 128), 256, 0, stream>>>(
        x_bf, W1t, hbuf, B_DIM, H2_DIM, D_DIM, pbuf, b1l, b1r);

    // W2t[n][k]: k<H -> W2l[k][n], else W2r[k-H][n]
    transpose_cast_kernel<<<dim3(D_DIM / 32, H_DIM / 32), 256, 0, stream>>>(W2l, H_DIM, D_DIM, W2t, H2_DIM);
    transpose_cast_kernel<<<dim3(D_DIM / 32, H_DIM / 32), 256, 0, stream>>>(W2r, H_DIM, D_DIM, W2t + H_DIM, H2_DIM);

    // out = h @ W2cat + p*b2l + (1-p)*b2r    -> f32 [B][D]
    gemm_kernel<0><<<dim3(D_DIM / 128, B_DIM / 128), 256, 0, stream>>>(
        hbuf, W2t, out, B_DIM, D_DIM, H2_DIM, pbuf, b2l, b2r);
}

// Round 2
// 457.536 us; speedup vs baseline: 1.3631x; 1.3631x over previous
//
#include <hip/hip_runtime.h>
#include <hip/hip_bf16.h>
#include <cstdint>
#include <cstddef>

#define B_DIM  8192
#define D_DIM  1024
#define H_DIM  4096
#define H2_DIM 8192

using bf16 = __hip_bfloat16;
typedef __attribute__((ext_vector_type(8))) short bf16x8;   // 8 bf16 in 4 VGPRs
typedef __attribute__((ext_vector_type(4))) float f32x4;    // MFMA accumulator

// ---------------------------------------------------------------- cast x -> bf16
__global__ __launch_bounds__(256) void cast_f32_to_bf16(const float* __restrict__ in,
                                                        bf16* __restrict__ out, int n_vec8) {
    int i = blockIdx.x * 256 + threadIdx.x;
    if (i >= n_vec8) return;
    const float4* src = reinterpret_cast<const float4*>(in) + (size_t)i * 2;
    float4 a = src[0], b = src[1];
    union { bf16 h[8]; int4 u; } r;
    r.h[0] = __float2bfloat16(a.x); r.h[1] = __float2bfloat16(a.y);
    r.h[2] = __float2bfloat16(a.z); r.h[3] = __float2bfloat16(a.w);
    r.h[4] = __float2bfloat16(b.x); r.h[5] = __float2bfloat16(b.y);
    r.h[6] = __float2bfloat16(b.z); r.h[7] = __float2bfloat16(b.w);
    reinterpret_cast<int4*>(out)[i] = r.u;
}

// ---------------------------------------------------------------- router p = sigmoid(x.Wr + br)
__global__ __launch_bounds__(256) void router_kernel(const float* __restrict__ x,
                                                     const float* __restrict__ Wr,
                                                     const float* __restrict__ br,
                                                     float* __restrict__ p) {
    int wave = threadIdx.x >> 6, lane = threadIdx.x & 63;
    int row = blockIdx.x * 4 + wave;
    const float* xr = x + (size_t)row * D_DIM;
    float sum = 0.f;
#pragma unroll
    for (int it = 0; it < 4; ++it) {
        int k = it * 256 + lane * 4;
        float4 xv = *reinterpret_cast<const float4*>(xr + k);
        float4 wv = *reinterpret_cast<const float4*>(Wr + k);
        sum += xv.x * wv.x + xv.y * wv.y + xv.z * wv.z + xv.w * wv.w;
    }
#pragma unroll
    for (int off = 32; off >= 1; off >>= 1) sum += __shfl_down(sum, off, 64);
    if (lane == 0) p[row] = 1.f / (1.f + expf(-(sum + br[0])));
}

// ---------------------------------------------------------------- transpose f32 [R][C] -> bf16 dst[c*dstLD + r]
__global__ __launch_bounds__(256) void transpose_cast_kernel(const float* __restrict__ src,
                                                             int R, int C,
                                                             bf16* __restrict__ dst, int dstLD) {
    __shared__ float tile[32][33];
    int c0 = blockIdx.x * 32, r0 = blockIdx.y * 32;
    int tx = threadIdx.x & 31, ty = threadIdx.x >> 5;  // ty: 0..7
#pragma unroll
    for (int i = 0; i < 32; i += 8)
        tile[ty + i][tx] = src[(size_t)(r0 + ty + i) * C + c0 + tx];
    __syncthreads();
#pragma unroll
    for (int i = 0; i < 32; i += 8)
        dst[(size_t)(c0 + ty + i) * dstLD + r0 + tx] = __float2bfloat16(tile[tx][ty + i]);
}

// ================================================================ 256-row counted-vmcnt GEMM
// C = A[M,K] * Bt[N,K]^T, tiles BM=256 x BN=NBH*128, BK=64, 512 threads (8 waves 2x4).
// LDS: 2 double-buffers of (2 A-halves + NBH B-halves) x [128 rows][64 bf16].
// T2 swizzle: LDS 16B-granule g holds global granule g ^ (row&7); source pre-swizzled
// (global_load_lds dest stays linear), ds_read applies the same XOR -> conflict-free b128.
// Pipeline: 2 tiles prefetched; per tile: {ds B+A_lo | MFMA_lo | ds A_hi} -> lgkm(0)+bar
// -> STAGE(t+2 into this buffer) -> MFMA_hi -> vmcnt(LPT, never 0 mid-loop) + bar.
template<int NBH, int EPI>
__global__ __launch_bounds__(512, 2) void gemm8(const bf16* __restrict__ A,
                                                const bf16* __restrict__ Bt,
                                                void* __restrict__ Cout,
                                                int N, int K, int NT, int nbx,
                                                const float* __restrict__ p,
                                                const float* __restrict__ bias_l,
                                                const float* __restrict__ bias_r) {
    constexpr int NREP   = 2 * NBH;          // 16-col frags per wave in N
    constexpr int HALF_B = 16384;            // 128 x 64 bf16
    constexpr int BUFB   = (2 + NBH) * HALF_B;
    constexpr int BN     = NBH * 128;
    __shared__ __align__(16) char lds[2 * BUFB];

    const int tid  = threadIdx.x;
    const int wid  = tid >> 6, lane = tid & 63;
    const int wr   = wid >> 2, wcn = wid & 3;

    // T1: bijective XCD-chunked swizzle (grid % 8 == 0)
    const int cpx     = (int)gridDim.x >> 3;
    const int logical = ((int)blockIdx.x & 7) * cpx + ((int)blockIdx.x >> 3);
    const int by = logical / nbx, bx = logical - by * nbx;
    const int bm = by * 256, bn = bx * BN;

    // ---- staging addresses (source carries the inverse swizzle)
    const int      srow = tid >> 3;                             // LDS row this thread fills
    const uint32_t coff = (uint32_t)(((tid & 7) ^ (srow & 7)) << 3);  // swizzled k-granule * 8
    uint32_t offA[2][2], offB[NBH][2];
#pragma unroll
    for (int h = 0; h < 2; ++h)
#pragma unroll
        for (int r = 0; r < 2; ++r)
            offA[h][r] = (uint32_t)(bm + h * 128 + r * 64 + srow) * (uint32_t)K + coff;
#pragma unroll
    for (int h = 0; h < NBH; ++h)
#pragma unroll
        for (int r = 0; r < 2; ++r)
            offB[h][r] = (uint32_t)(bn + h * 128 + r * 64 + srow) * (uint32_t)K + coff;

#define STAGE(PAR, KT) do {                                                                  \
    const uint32_t k64_ = (uint32_t)(KT) * 64u;                                              \
    _Pragma("unroll") for (int h_ = 0; h_ < 2; ++h_)                                         \
      _Pragma("unroll") for (int r_ = 0; r_ < 2; ++r_)                                       \
        __builtin_amdgcn_global_load_lds(                                                    \
          (const __attribute__((address_space(1))) uint32_t*)(A + (size_t)(offA[h_][r_] + k64_)), \
          (__attribute__((address_space(3))) uint32_t*)(lds + (PAR)*BUFB + h_*HALF_B + r_*8192 + wid*1024), \
          16, 0, 0);                                                                         \
    _Pragma("unroll") for (int h_ = 0; h_ < NBH; ++h_)                                       \
      _Pragma("unroll") for (int r_ = 0; r_ < 2; ++r_)                                       \
        __builtin_amdgcn_global_load_lds(                                                    \
          (const __attribute__((address_space(1))) uint32_t*)(Bt + (size_t)(offB[h_][r_] + k64_)), \
          (__attribute__((address_space(3))) uint32_t*)(lds + (PAR)*BUFB + (2+h_)*HALF_B + r_*8192 + wid*1024), \
          16, 0, 0);                                                                         \
} while (0)

    // ---- ds_read bases (swizzled): addr = base + m*2048, kk flips bit 6 via XOR
    const int      lrow  = lane & 15, kg = lane >> 4;
    const uint32_t s0    = (uint32_t)((kg ^ (lrow & 7)) << 4);
    const uint32_t baseA = (uint32_t)(wr * HALF_B + lrow * 128) + s0;
    const int      colt0 = wcn * (NREP * 16);
    const uint32_t baseB = (uint32_t)((2 + (colt0 >> 7)) * HALF_B + ((colt0 & 127) + lrow) * 128) + s0;

#define RD(off) (*reinterpret_cast<const bf16x8*>(lds + (off)))

    f32x4 acc[8][NREP];
#pragma unroll
    for (int m = 0; m < 8; ++m)
#pragma unroll
        for (int n = 0; n < NREP; ++n) acc[m][n] = (f32x4){0.f, 0.f, 0.f, 0.f};

#define VM_WAIT_STEADY() do {                                              \
    if (NBH == 2) asm volatile("s_waitcnt vmcnt(8)" ::: "memory");         \
    else          asm volatile("s_waitcnt vmcnt(6)" ::: "memory");         \
} while (0)

#define TILE_BODY(PAR, KT, STG, LASTT) do {                                                   \
    bf16x8 bf_[NREP][2], af_[4][2];                                                           \
    _Pragma("unroll") for (int n = 0; n < NREP; ++n)                                          \
      _Pragma("unroll") for (int kk = 0; kk < 2; ++kk)                                        \
        bf_[n][kk] = RD(((uint32_t)((PAR)*BUFB) + baseB + (uint32_t)(n*2048)) ^ (uint32_t)(kk*64)); \
    _Pragma("unroll") for (int m = 0; m < 4; ++m)                                             \
      _Pragma("unroll") for (int kk = 0; kk < 2; ++kk)                                        \
        af_[m][kk] = RD(((uint32_t)((PAR)*BUFB) + baseA + (uint32_t)(m*2048)) ^ (uint32_t)(kk*64)); \
    __builtin_amdgcn_s_setprio(1);                                                            \
    _Pragma("unroll") for (int m = 0; m < 4; ++m)                                             \
      _Pragma("unroll") for (int n = 0; n < NREP; ++n)                                        \
        _Pragma("unroll") for (int kk = 0; kk < 2; ++kk)                                      \
          acc[m][n] = __builtin_amdgcn_mfma_f32_16x16x32_bf16(af_[m][kk], bf_[n][kk], acc[m][n], 0, 0, 0); \
    __builtin_amdgcn_s_setprio(0);                                                            \
    _Pragma("unroll") for (int m = 0; m < 4; ++m)                                             \
      _Pragma("unroll") for (int kk = 0; kk < 2; ++kk)                                        \
        af_[m][kk] = RD(((uint32_t)((PAR)*BUFB) + baseA + (uint32_t)(8192 + m*2048)) ^ (uint32_t)(kk*64)); \
    __builtin_amdgcn_sched_barrier(0);                                                        \
    asm volatile("s_waitcnt lgkmcnt(0)" ::: "memory");                                        \
    __builtin_amdgcn_sched_barrier(0);                                                        \
    __builtin_amdgcn_s_barrier();                                                             \
    __builtin_amdgcn_sched_barrier(0);                                                        \
    if (STG) { STAGE(PAR, (KT) + 2); }                                                        \
    __builtin_amdgcn_sched_barrier(0);                                                        \
    __builtin_amdgcn_s_setprio(1);                                                            \
    _Pragma("unroll") for (int m = 0; m < 4; ++m)                                             \
      _Pragma("unroll") for (int n = 0; n < NREP; ++n)                                        \
        _Pragma("unroll") for (int kk = 0; kk < 2; ++kk)                                      \
          acc[4+m][n] = __builtin_amdgcn_mfma_f32_16x16x32_bf16(af_[m][kk], bf_[n][kk], acc[4+m][n], 0, 0, 0); \
    __builtin_amdgcn_s_setprio(0);                                                            \
    if (!(LASTT)) {                                                                           \
      __builtin_amdgcn_sched_barrier(0);                                                      \
      if (STG) { VM_WAIT_STEADY(); }                                                          \
      else     { asm volatile("s_waitcnt vmcnt(0)" ::: "memory"); }                           \
      __builtin_amdgcn_sched_barrier(0);                                                      \
      __builtin_amdgcn_s_barrier();                                                           \
      __builtin_amdgcn_sched_barrier(0);                                                      \
    }                                                                                         \
} while (0)

    // prologue: prefetch tiles 0 and 1
    STAGE(0, 0);
    STAGE(1, 1);
    VM_WAIT_STEADY();                 // tile 0 landed; tile 1 in flight
    __builtin_amdgcn_sched_barrier(0);
    __builtin_amdgcn_s_barrier();
    __builtin_amdgcn_sched_barrier(0);

    // main loop: tiles 0..NT-3 stage tile+2 (NT even, >= 4)
    int kt = 0;
    for (; kt < NT - 2; kt += 2) {
        TILE_BODY(0, kt,     true, false);
        TILE_BODY(1, kt + 1, true, false);
    }
    TILE_BODY(0, NT - 2, false, false);   // drains vmcnt(0) -> tile NT-1 ready
    TILE_BODY(1, NT - 1, false, true);    // final tile, no trailing barrier

    // ---- epilogue: C/D layout col = lane&15, row = (lane>>4)*4 + j
    const int crow0 = bm + wr * 128 + (kg << 2);
    const int ccol0 = bn + wcn * (NREP * 16) + lrow;

    if (EPI == 1) {
        bf16* __restrict__ Ho = (bf16*)Cout;
#pragma unroll
        for (int n = 0; n < NREP; ++n) {
            const int col = ccol0 + n * 16;
            const bool left = col < H_DIM;
            const float bias = left ? bias_l[col] : bias_r[col - H_DIM];
#pragma unroll
            for (int m = 0; m < 8; ++m) {
#pragma unroll
                for (int j = 0; j < 4; ++j) {
                    const int row = crow0 + m * 16 + j;
                    const float pw = p[row];
                    const float scale = left ? pw : 1.f - pw;
                    const float v = fmaxf(acc[m][n][j] + bias, 0.f) * scale;
                    Ho[(size_t)row * N + col] = __float2bfloat16(v);
                }
            }
        }
    } else {
        float* __restrict__ Co = (float*)Cout;
#pragma unroll
        for (int n = 0; n < NREP; ++n) {
            const int col = ccol0 + n * 16;
            const float bl = bias_l[col];
            const float brr = bias_r[col];
#pragma unroll
            for (int m = 0; m < 8; ++m) {
#pragma unroll
                for (int j = 0; j < 4; ++j) {
                    const int row = crow0 + m * 16 + j;
                    const float pw = p[row];
                    Co[(size_t)row * N + col] = acc[m][n][j] + pw * bl + (1.f - pw) * brr;
                }
            }
        }
    }
#undef TILE_BODY
#undef VM_WAIT_STEADY
#undef RD
#undef STAGE
}

// ---------------------------------------------------------------- launch
extern "C" void kernel_launch(void* const* d_in, const int* in_sizes, int n_in,
                              void* d_out, int out_size, void* d_ws, size_t ws_size,
                              hipStream_t stream) {
    const float* x   = (const float*)d_in[0];
    const float* Wr  = (const float*)d_in[1];
    const float* br  = (const float*)d_in[2];
    const float* W1l = (const float*)d_in[3];
    const float* b1l = (const float*)d_in[4];
    const float* W2l = (const float*)d_in[5];
    const float* b2l = (const float*)d_in[6];
    const float* W1r = (const float*)d_in[7];
    const float* b1r = (const float*)d_in[8];
    const float* W2r = (const float*)d_in[9];
    const float* b2r = (const float*)d_in[10];
    float* out = (float*)d_out;

    char* ws = (char*)d_ws;
    // workspace layout (~160 MB):
    //   [0,16MB)     x_bf16 [B][D] bf16   (dead after gemm1; reused for W2t)
    //   [16,32MB)    W1t    [2H][D] bf16
    //   [32,160MB)   h      [B][2H] bf16
    //   [160MB,+32K) p      [B] f32
    bf16*  x_bf = (bf16*)(ws);
    bf16*  W1t  = (bf16*)(ws + (size_t)(16u << 20));
    bf16*  hbuf = (bf16*)(ws + (size_t)(32u << 20));
    float* pbuf = (float*)(ws + (size_t)(160u << 20));
    bf16*  W2t  = x_bf;   // aliased: written only after gemm1 consumed x_bf

    cast_f32_to_bf16<<<(B_DIM * D_DIM / 8 + 255) / 256, 256, 0, stream>>>(x, x_bf, B_DIM * D_DIM / 8);
    router_kernel<<<B_DIM / 4, 256, 0, stream>>>(x, Wr, br, pbuf);

    // W1t[n][k]: n<H -> W1l[k][n], else W1r[k][n-H]
    transpose_cast_kernel<<<dim3(H_DIM / 32, D_DIM / 32), 256, 0, stream>>>(W1l, D_DIM, H_DIM, W1t, D_DIM);
    transpose_cast_kernel<<<dim3(H_DIM / 32, D_DIM / 32), 256, 0, stream>>>(W1r, D_DIM, H_DIM,
                                                                            W1t + (size_t)H_DIM * D_DIM, D_DIM);
    // h = relu(x @ W1cat + b1cat) * {p | 1-p}   -> bf16 [B][2H]
    // grid 32x32=1024 blocks, BN=256, NT=16, nbx=32
    gemm8<2, 1><<<1024, 512, 0, stream>>>(x_bf, W1t, hbuf, H2_DIM, D_DIM, D_DIM / 64, 32,
                                          pbuf, b1l, b1r);

    // W2t[n][k]: k<H -> W2l[k][n], else W2r[k-H][n]
    transpose_cast_kernel<<<dim3(D_DIM / 32, H_DIM / 32), 256, 0, stream>>>(W2l, H_DIM, D_DIM, W2t, H2_DIM);
    transpose_cast_kernel<<<dim3(D_DIM / 32, H_DIM / 32), 256, 0, stream>>>(W2r, H_DIM, D_DIM, W2t + H_DIM, H2_DIM);

    // out = h @ W2cat + p*b2l + (1-p)*b2r    -> f32 [B][D]
    // grid 8x32=256 blocks, BN=128, NT=128, nbx=8
    gemm8<1, 0><<<256, 512, 0, stream>>>(hbuf, W2t, out, D_DIM, H2_DIM, H2_DIM / 64, 8,
                                         pbuf, b2l, b2r);
}